// Round 2
// baseline (4811.396 us; speedup 1.0000x reference)
//
#include <hip/hip_runtime.h>
#include <math.h>

// ---------------------------------------------------------------------------
// GraphAutoEncoder forward on MI355X. All f32. Round 1: fix edge_index dtype
// (harness provides integer inputs as int32, NOT int64).
//   - deg/dinv/norm computed once (shared by all 8 gcn_props)
//   - gcn_prop: edge-parallel scatter-add with f32 atomics
//   - GEMM: 64x64x32 tiled f32, 4x4 register tile
//   - GATv2: logits -> atomic max -> exp+sum -> weighted scatter
//   - W5 layer reordered: prop(x)@W5 instead of prop(x@W5)  (linearity)
// ---------------------------------------------------------------------------

static constexpr int HEADS = 4;

__global__ void fill_kernel(float* __restrict__ p, float v, long long n) {
  long long i = (long long)blockIdx.x * blockDim.x + threadIdx.x;
  long long stride = (long long)gridDim.x * blockDim.x;
  for (; i < n; i += stride) p[i] = v;
}

__global__ void deg_kernel(const int* __restrict__ ei, float* __restrict__ deg, int E) {
  int i = blockIdx.x * blockDim.x + threadIdx.x;
  int stride = gridDim.x * blockDim.x;
  for (; i < E; i += stride) {
    atomicAdd(&deg[ei[E + i]], 1.0f);
  }
}

__global__ void dinv_kernel(const float* __restrict__ deg, float* __restrict__ dinv, int N) {
  int i = blockIdx.x * blockDim.x + threadIdx.x;
  if (i < N) {
    float d = deg[i];
    dinv[i] = d > 0.f ? 1.0f / sqrtf(d) : 0.f;
  }
}

__global__ void norm_kernel(const int* __restrict__ ei, const float* __restrict__ dinv,
                            float* __restrict__ normv, int E, int N) {
  int E2 = E + N;
  int i = blockIdx.x * blockDim.x + threadIdx.x;
  int stride = gridDim.x * blockDim.x;
  for (; i < E2; i += stride) {
    int s, d;
    if (i < E) { s = ei[i]; d = ei[E + i]; } else { s = d = i - E; }
    normv[i] = dinv[s] * dinv[d];
  }
}

// out[dst] += norm[e] * h[src]  over all edges; one work item per (edge, dim)
__global__ void prop_kernel(const float* __restrict__ h, const int* __restrict__ ei,
                            const float* __restrict__ normv, float* __restrict__ out,
                            int E, int N, int logD) {
  const int D = 1 << logD;
  const long long total = (long long)(E + N) << logD;
  long long i = (long long)blockIdx.x * blockDim.x + threadIdx.x;
  long long stride = (long long)gridDim.x * blockDim.x;
  for (; i < total; i += stride) {
    int e = (int)(i >> logD);
    int d = (int)(i & (D - 1));
    int s, t;
    if (e < E) { s = ei[e]; t = ei[E + e]; } else { s = t = e - E; }
    atomicAdd(&out[(long long)t * D + d], normv[e] * h[(long long)s * D + d]);
  }
}

// Tiled f32 GEMM: C[N x M] = A[N x K] @ W[K x M]  (+bias, +relu per EPI)
// EPI: 0 = none, 2 = bias + relu
template <int EPI>
__global__ __launch_bounds__(256) void gemm_kernel(const float* __restrict__ A,
                                                   const float* __restrict__ W,
                                                   const float* __restrict__ bias,
                                                   float* __restrict__ C,
                                                   int N, int K, int M) {
  constexpr int BM = 64, BN = 64, BK = 32, TM = 4, TN = 4;
  __shared__ float As[BK][BM + 1];  // transposed tile, +1 pad: conflict-free
  __shared__ float Bs[BK][BN];

  const int row0 = blockIdx.y * BM;
  const int col0 = blockIdx.x * BN;
  const int tid = threadIdx.x;
  const int tr = (tid / 16) * TM;
  const int tc = (tid % 16) * TN;

  float acc[TM][TN] = {};

  for (int k0 = 0; k0 < K; k0 += BK) {
    for (int i = tid; i < BM * BK; i += 256) {
      int r = i / BK, k = i % BK;
      int gr = row0 + r, gk = k0 + k;
      As[k][r] = (gr < N && gk < K) ? A[(long long)gr * K + gk] : 0.f;
    }
    for (int i = tid; i < BK * BN; i += 256) {
      int k = i / BN, c = i % BN;
      int gk = k0 + k, gc = col0 + c;
      Bs[k][c] = (gk < K && gc < M) ? W[(long long)gk * M + gc] : 0.f;
    }
    __syncthreads();
#pragma unroll
    for (int k = 0; k < BK; ++k) {
      float a[TM], b[TN];
#pragma unroll
      for (int i = 0; i < TM; ++i) a[i] = As[k][tr + i];
#pragma unroll
      for (int j = 0; j < TN; ++j) b[j] = Bs[k][tc + j];
#pragma unroll
      for (int i = 0; i < TM; ++i)
#pragma unroll
        for (int j = 0; j < TN; ++j) acc[i][j] += a[i] * b[j];
    }
    __syncthreads();
  }

#pragma unroll
  for (int i = 0; i < TM; ++i) {
    int gr = row0 + tr + i;
    if (gr >= N) continue;
#pragma unroll
    for (int j = 0; j < TN; ++j) {
      int gc = col0 + tc + j;
      if (gc >= M) continue;
      float v = acc[i][j];
      if (EPI >= 1) v += bias[gc];
      if (EPI == 2) v = fmaxf(v, 0.f);
      C[(long long)gr * M + gc] = v;
    }
  }
}

// GATv2: per-(edge, head) attention logit + atomic segment max
__global__ void gat_logits_kernel(const float* __restrict__ xl, const float* __restrict__ xr,
                                  const float* __restrict__ att, const int* __restrict__ ei,
                                  float* __restrict__ ea, float* __restrict__ amax,
                                  int E, int N) {
  const long long total = (long long)(E + N) * HEADS;
  long long i = (long long)blockIdx.x * blockDim.x + threadIdx.x;
  long long stride = (long long)gridDim.x * blockDim.x;
  for (; i < total; i += stride) {
    int e = (int)(i >> 2);
    int hh = (int)(i & 3);
    int s, t;
    if (e < E) { s = ei[e]; t = ei[E + e]; } else { s = t = e - E; }
    const float* pl = xl + (long long)s * 128 + hh * 32;
    const float* pr = xr + (long long)t * 128 + hh * 32;
    const float* pa = att + hh * 32;
    float acc = 0.f;
#pragma unroll
    for (int c = 0; c < 32; ++c) {
      float v = pl[c] + pr[c];
      v = v >= 0.f ? v : 0.2f * v;
      acc += v * pa[c];
    }
    ea[i] = acc;
    float* ap = &amax[(long long)t * HEADS + hh];
    // monotone-bits float atomic max (init -inf)
    if (acc >= 0.f) atomicMax((int*)ap, __float_as_int(acc));
    else            atomicMin((unsigned int*)ap, __float_as_uint(acc));
  }
}

__global__ void gat_exp_kernel(const int* __restrict__ ei, float* __restrict__ ea,
                               const float* __restrict__ amax, float* __restrict__ asum,
                               int E, int N) {
  const long long total = (long long)(E + N) * HEADS;
  long long i = (long long)blockIdx.x * blockDim.x + threadIdx.x;
  long long stride = (long long)gridDim.x * blockDim.x;
  for (; i < total; i += stride) {
    int e = (int)(i >> 2);
    int hh = (int)(i & 3);
    int t = (e < E) ? ei[E + e] : e - E;
    float v = expf(ea[i] - amax[(long long)t * HEADS + hh]);
    ea[i] = v;
    atomicAdd(&asum[(long long)t * HEADS + hh], v);
  }
}

__global__ void gat_scatter_kernel(const int* __restrict__ ei, const float* __restrict__ ea,
                                   const float* __restrict__ asum, const float* __restrict__ xl,
                                   float* __restrict__ out, int E, int N) {
  const long long total = (long long)(E + N) * 128;
  long long i = (long long)blockIdx.x * blockDim.x + threadIdx.x;
  long long stride = (long long)gridDim.x * blockDim.x;
  for (; i < total; i += stride) {
    int e = (int)(i >> 7);
    int d = (int)(i & 127);
    int s, t;
    if (e < E) { s = ei[e]; t = ei[E + e]; } else { s = t = e - E; }
    int hh = d >> 5;
    float w = ea[(long long)e * HEADS + hh] / (asum[(long long)t * HEADS + hh] + 1e-16f);
    atomicAdd(&out[(long long)t * 128 + d], w * xl[(long long)s * 128 + d]);
  }
}

// out = (relu?)(in + bias[d])   (out may alias in)
__global__ void bias_act_kernel(const float* in, const float* __restrict__ bias, float* out,
                                long long total, int logD, int do_relu) {
  long long i = (long long)blockIdx.x * blockDim.x + threadIdx.x;
  long long stride = (long long)gridDim.x * blockDim.x;
  const int mask = (1 << logD) - 1;
  for (; i < total; i += stride) {
    float v = in[i] + bias[(int)(i & mask)];
    if (do_relu) v = fmaxf(v, 0.f);
    out[i] = v;
  }
}

// x = a*x + b*y
__global__ void axpby_kernel(float* x, const float* __restrict__ y, float a, float b, long long n) {
  long long i = (long long)blockIdx.x * blockDim.x + threadIdx.x;
  long long stride = (long long)gridDim.x * blockDim.x;
  for (; i < n; i += stride) x[i] = a * x[i] + b * y[i];
}

// out = relu(c1*h + c2*t)   (out may alias h or t)
__global__ void combine_relu_kernel(const float* h, const float* t, float* out,
                                    float c1, float c2, long long n) {
  long long i = (long long)blockIdx.x * blockDim.x + threadIdx.x;
  long long stride = (long long)gridDim.x * blockDim.x;
  for (; i < n; i += stride) out[i] = fmaxf(c1 * h[i] + c2 * t[i], 0.f);
}

extern "C" void kernel_launch(void* const* d_in, const int* in_sizes, int n_in,
                              void* d_out, int out_size, void* d_ws, size_t ws_size,
                              hipStream_t stream) {
  const float* x  = (const float*)d_in[0];
  const int*   ei = (const int*)d_in[1];   // int32! harness materializes ints as int32
  const float* W1 = (const float*)d_in[2];  const float* b1 = (const float*)d_in[3];
  const float* W2 = (const float*)d_in[4];  const float* b2 = (const float*)d_in[5];
  const float* W3 = (const float*)d_in[6];  const float* b3 = (const float*)d_in[7];
  const float* W4 = (const float*)d_in[8];  const float* b4 = (const float*)d_in[9];
  const float* Wl = (const float*)d_in[10]; const float* Wr = (const float*)d_in[11];
  const float* att= (const float*)d_in[12]; const float* bg = (const float*)d_in[13];
  const float* Wc1= (const float*)d_in[14];
  const float* W5 = (const float*)d_in[15]; const float* b5 = (const float*)d_in[16];
  const float* Wc2= (const float*)d_in[17];
  const float* Wo = (const float*)d_in[18]; const float* bo = (const float*)d_in[19];

  const int N = in_sizes[0] / 300;
  const int E = in_sizes[1] / 2;
  const int E2 = E + N;
  float* out = (float*)d_out;

  const float BETA = 0.04879016416943205f;  // log(0.1/2 + 1)
  const float OMB  = 1.0f - BETA;

  // workspace carve-up (~250 MB)
  float* ws   = (float*)d_ws;
  float* normv= ws;  ws += E2;
  float* x1   = ws;  ws += (long long)N * 256;
  float* x2   = ws;  ws += (long long)N * 128;
  float* bufA = ws;  ws += (long long)N * 256;
  float* bufB = ws;  ws += (long long)N * 256;
  float* bufC = ws;  ws += (long long)N * 256;
  float* ea   = ws;  ws += (long long)E2 * HEADS;
  float* amax = ws;  ws += (long long)N * HEADS;
  float* asum = ws;  ws += (long long)N * HEADS;
  // deg/dinv are setup-only: overlap them with the (not-yet-used) ea region
  float* deg  = ea;
  float* dinv = ea + N;

  auto gemm = [&](const float* A, const float* Wm, const float* bias, float* C,
                  int n, int K, int M, int epi) {
    dim3 grid((M + 63) / 64, (n + 63) / 64);
    if (epi == 0) gemm_kernel<0><<<grid, 256, 0, stream>>>(A, Wm, bias, C, n, K, M);
    else          gemm_kernel<2><<<grid, 256, 0, stream>>>(A, Wm, bias, C, n, K, M);
  };
  auto prop = [&](const float* hsrc, float* dst, int logD) {
    hipMemsetAsync(dst, 0, (size_t)N * (1u << logD) * sizeof(float), stream);
    long long total = (long long)E2 << logD;
    int blocks = (int)(((total + 255) / 256 < 8192) ? (total + 255) / 256 : 8192);
    prop_kernel<<<blocks, 256, 0, stream>>>(hsrc, ei, normv, dst, E, N, logD);
  };
  auto bias_act = [&](const float* in, const float* b, float* o, long long total, int logD, int relu) {
    int blocks = (int)(((total + 255) / 256 < 4096) ? (total + 255) / 256 : 4096);
    bias_act_kernel<<<blocks, 256, 0, stream>>>(in, b, o, total, logD, relu);
  };

  // ---- norm (shared) ----
  fill_kernel<<<256, 256, 0, stream>>>(deg, 1.0f, N);  // self-loop contributes 1
  deg_kernel<<<2048, 256, 0, stream>>>(ei, deg, E);
  dinv_kernel<<<(N + 255) / 256, 256, 0, stream>>>(deg, dinv, N);
  norm_kernel<<<2048, 256, 0, stream>>>(ei, dinv, normv, E, N);

  // ---- layer 1: x1 = relu(prop(x@W1)+b1) ----
  gemm(x, W1, nullptr, bufA, N, 300, 256, 0);
  prop(bufA, bufB, 8);
  bias_act(bufB, b1, x1, (long long)N * 256, 8, 1);

  // ---- layer 2: x2 = relu(prop(x1@W2)+b2) ----
  gemm(x1, W2, nullptr, bufA, N, 256, 128, 0);
  prop(bufA, bufB, 7);
  bias_act(bufB, b2, x2, (long long)N * 128, 7, 1);

  // ---- layer 3: relu(prop(x2@W3)+b3) ----
  gemm(x2, W3, nullptr, bufA, N, 128, 64, 0);
  prop(bufA, bufB, 6);
  bias_act(bufB, b3, bufB, (long long)N * 64, 6, 1);

  // ---- layer 4: relu(prop(.@W4)+b4) ----
  gemm(bufB, W4, nullptr, bufA, N, 64, 32, 0);
  prop(bufA, bufB, 5);
  bias_act(bufB, b4, bufB, (long long)N * 32, 5, 1);  // cur (N x 32) in bufB

  // ---- GATv2 ----
  gemm(bufB, Wl, nullptr, bufA, N, 32, 128, 0);  // xl in bufA
  gemm(bufB, Wr, nullptr, bufC, N, 32, 128, 0);  // xr in bufC
  fill_kernel<<<256, 256, 0, stream>>>(amax, -INFINITY, (long long)N * HEADS);
  gat_logits_kernel<<<4096, 256, 0, stream>>>(bufA, bufC, att, ei, ea, amax, E, N);
  hipMemsetAsync(asum, 0, (size_t)N * HEADS * sizeof(float), stream);
  gat_exp_kernel<<<4096, 256, 0, stream>>>(ei, ea, amax, asum, E, N);
  hipMemsetAsync(bufB, 0, (size_t)N * 128 * sizeof(float), stream);
  gat_scatter_kernel<<<8192, 256, 0, stream>>>(ei, ea, asum, bufA, bufB, E, N);
  bias_act(bufB, bg, bufB, (long long)N * 128, 7, 1);  // x3 (N x 128) in bufB

  // ---- GCN2 #1: relu((1-B)*h + B*(h@Wc1)), h = 0.5*prop(x3) + 0.5*x2 ----
  prop(bufB, bufA, 7);
  axpby_kernel<<<4096, 256, 0, stream>>>(bufA, x2, 0.5f, 0.5f, (long long)N * 128);
  gemm(bufA, Wc1, nullptr, bufC, N, 128, 128, 0);
  combine_relu_kernel<<<4096, 256, 0, stream>>>(bufA, bufC, bufA, OMB, BETA, (long long)N * 128);
  // result (N x 128) in bufA

  // ---- W5 layer: relu(prop(x@W5)+b5) == relu(prop(x)@W5+b5) ----
  prop(bufA, bufB, 7);
  gemm(bufB, W5, b5, bufC, N, 128, 256, 2);  // relu fused; (N x 256) in bufC

  // ---- GCN2 #2: h = 0.5*prop(.)+0.5*x1 ----
  prop(bufC, bufA, 8);
  axpby_kernel<<<4096, 256, 0, stream>>>(bufA, x1, 0.5f, 0.5f, (long long)N * 256);
  gemm(bufA, Wc2, nullptr, bufB, N, 256, 256, 0);
  combine_relu_kernel<<<4096, 256, 0, stream>>>(bufA, bufB, bufB, OMB, BETA, (long long)N * 256);
  // result (N x 256) in bufB

  // ---- final: prop(x@Wo) + bo ----
  gemm(bufB, Wo, nullptr, bufA, N, 256, 128, 0);
  prop(bufA, out, 7);
  bias_act(out, bo, out, (long long)N * 128, 7, 0);
}

// Round 3
// 1948.399 us; speedup vs baseline: 2.4694x; 2.4694x over previous
//
#include <hip/hip_runtime.h>
#include <math.h>

// ---------------------------------------------------------------------------
// GraphAutoEncoder forward on MI355X. All f32. Round 2:
//   - CSR (sorted-by-dst) built on device each launch; all propagations are
//     per-node gather-sums (NO scatter atomics -> kills the 850MB/dispatch
//     memory-side atomic write traffic seen in round 1 counters)
//   - prop epilogues fused (bias/relu/0.5*x0 mix)
//   - GAT: per-node wave softmax (no atomics), CSR-ordered weights, gather
//   - GEMM: 64x64x32 tiled f32 (unchanged)
//   - W5 layer reordered: prop(x)@W5 instead of prop(x@W5)  (linearity)
// ---------------------------------------------------------------------------

static constexpr int HEADS = 4;

// ---------------- CSR build ----------------

__global__ void deg_kernel(const int* __restrict__ ei, int* __restrict__ deg, int E) {
  int i = blockIdx.x * blockDim.x + threadIdx.x;
  int stride = gridDim.x * blockDim.x;
  for (; i < E; i += stride) atomicAdd(&deg[ei[E + i]], 1);
}

__global__ void dinv_kernel(const int* __restrict__ deg, float* __restrict__ dinv, int N) {
  int i = blockIdx.x * blockDim.x + threadIdx.x;
  if (i < N) dinv[i] = rsqrtf((float)(deg[i] + 1));  // +1 self-loop
}

// inclusive scan, chunk of 2048 per block (256 thr x 8), partial sums out
__global__ __launch_bounds__(256) void scan_block_kernel(const int* __restrict__ in,
                                                         int* __restrict__ out,
                                                         int* __restrict__ bsum, int n) {
  __shared__ int lds[256];
  const int base = blockIdx.x * 2048;
  const int tid = threadIdx.x;
  int v[8];
  int s = 0;
#pragma unroll
  for (int k = 0; k < 8; ++k) {
    int idx = base + tid * 8 + k;
    v[k] = (idx < n) ? in[idx] : 0;
    s += v[k];
  }
  lds[tid] = s;
  __syncthreads();
  for (int off = 1; off < 256; off <<= 1) {
    int t = (tid >= off) ? lds[tid - off] : 0;
    __syncthreads();
    lds[tid] += t;
    __syncthreads();
  }
  int run = (tid > 0) ? lds[tid - 1] : 0;
#pragma unroll
  for (int k = 0; k < 8; ++k) {
    int idx = base + tid * 8 + k;
    run += v[k];
    if (idx < n) out[idx] = run;
  }
  if (tid == 255) bsum[blockIdx.x] = lds[255];
}

__global__ void scan_small_kernel(int* bsum, int nb) {
  if (threadIdx.x == 0 && blockIdx.x == 0) {
    int run = 0;
    for (int i = 0; i < nb; ++i) { int t = bsum[i]; bsum[i] = run; run += t; }
  }
}

__global__ __launch_bounds__(256) void scan_add_kernel(int* __restrict__ out,
                                                       const int* __restrict__ bsum, int n) {
  int idx = blockIdx.x * 2048 + threadIdx.x;
  const int add = bsum[blockIdx.x];
#pragma unroll
  for (int k = 0; k < 8; ++k, idx += 256)
    if (idx < n) out[idx] += add;
}

__global__ void fill_csr_kernel(const int* __restrict__ ei, const float* __restrict__ dinv,
                                const int* __restrict__ rowptr, int* __restrict__ fill,
                                int* __restrict__ cols, int* __restrict__ eids,
                                float* __restrict__ vals, int E) {
  int e = blockIdx.x * blockDim.x + threadIdx.x;
  int stride = gridDim.x * blockDim.x;
  for (; e < E; e += stride) {
    int s = ei[e], t = ei[E + e];
    int pos = rowptr[t] + atomicAdd(&fill[t], 1);
    cols[pos] = s;
    eids[pos] = e;
    vals[pos] = dinv[s] * dinv[t];
  }
}

// ---------------- propagation (CSR gather, float4) ----------------
// EPI: 0 none | 1 +bias | 2 relu(+bias) | 3 0.5*acc+0.5*x0
template <int D, int EPI>
__global__ __launch_bounds__(256) void prop_csr_kernel(
    const float4* __restrict__ h, const int* __restrict__ rowptr,
    const int* __restrict__ cols, const float* __restrict__ vals,
    const float* __restrict__ dinv, const float* __restrict__ bx,
    float4* __restrict__ out, int N) {
  constexpr int TPN = D / 4;       // float4 lanes per node
  constexpr int NPB = 256 / TPN;   // nodes per block
  const int node = blockIdx.x * NPB + threadIdx.x / TPN;
  const int q = threadIdx.x % TPN;
  if (node >= N) return;
  const int start = rowptr[node], end = rowptr[node + 1];
  float4 acc = make_float4(0.f, 0.f, 0.f, 0.f);
  int j = start;
  for (; j + 1 < end; j += 2) {
    float v0 = vals[j], v1 = vals[j + 1];
    float4 a = h[(long long)cols[j] * TPN + q];
    float4 b = h[(long long)cols[j + 1] * TPN + q];
    acc.x += v0 * a.x + v1 * b.x;
    acc.y += v0 * a.y + v1 * b.y;
    acc.z += v0 * a.z + v1 * b.z;
    acc.w += v0 * a.w + v1 * b.w;
  }
  if (j < end) {
    float v = vals[j];
    float4 a = h[(long long)cols[j] * TPN + q];
    acc.x += v * a.x; acc.y += v * a.y; acc.z += v * a.z; acc.w += v * a.w;
  }
  {
    float di = dinv[node];
    float sv = di * di;
    float4 a = h[(long long)node * TPN + q];
    acc.x += sv * a.x; acc.y += sv * a.y; acc.z += sv * a.z; acc.w += sv * a.w;
  }
  float4 r;
  if (EPI == 0) {
    r = acc;
  } else if (EPI == 1 || EPI == 2) {
    float4 b = ((const float4*)bx)[q];
    r.x = acc.x + b.x; r.y = acc.y + b.y; r.z = acc.z + b.z; r.w = acc.w + b.w;
    if (EPI == 2) {
      r.x = fmaxf(r.x, 0.f); r.y = fmaxf(r.y, 0.f);
      r.z = fmaxf(r.z, 0.f); r.w = fmaxf(r.w, 0.f);
    }
  } else {  // EPI == 3
    float4 x0 = ((const float4*)bx)[(long long)node * TPN + q];
    r.x = 0.5f * (acc.x + x0.x); r.y = 0.5f * (acc.y + x0.y);
    r.z = 0.5f * (acc.z + x0.z); r.w = 0.5f * (acc.w + x0.w);
  }
  out[(long long)node * TPN + q] = r;
}

// ---------------- GEMM (f32 tiled) ----------------
// EPI: 0 = none, 2 = bias + relu
template <int EPI>
__global__ __launch_bounds__(256) void gemm_kernel(const float* __restrict__ A,
                                                   const float* __restrict__ W,
                                                   const float* __restrict__ bias,
                                                   float* __restrict__ C,
                                                   int N, int K, int M) {
  constexpr int BM = 64, BN = 64, BK = 32, TM = 4, TN = 4;
  __shared__ float As[BK][BM + 1];
  __shared__ float Bs[BK][BN];

  const int row0 = blockIdx.y * BM;
  const int col0 = blockIdx.x * BN;
  const int tid = threadIdx.x;
  const int tr = (tid / 16) * TM;
  const int tc = (tid % 16) * TN;

  float acc[TM][TN] = {};

  for (int k0 = 0; k0 < K; k0 += BK) {
    for (int i = tid; i < BM * BK; i += 256) {
      int r = i / BK, k = i % BK;
      int gr = row0 + r, gk = k0 + k;
      As[k][r] = (gr < N && gk < K) ? A[(long long)gr * K + gk] : 0.f;
    }
    for (int i = tid; i < BK * BN; i += 256) {
      int k = i / BN, c = i % BN;
      int gk = k0 + k, gc = col0 + c;
      Bs[k][c] = (gk < K && gc < M) ? W[(long long)gk * M + gc] : 0.f;
    }
    __syncthreads();
#pragma unroll
    for (int k = 0; k < BK; ++k) {
      float a[TM], b[TN];
#pragma unroll
      for (int i = 0; i < TM; ++i) a[i] = As[k][tr + i];
#pragma unroll
      for (int j = 0; j < TN; ++j) b[j] = Bs[k][tc + j];
#pragma unroll
      for (int i = 0; i < TM; ++i)
#pragma unroll
        for (int j = 0; j < TN; ++j) acc[i][j] += a[i] * b[j];
    }
    __syncthreads();
  }

#pragma unroll
  for (int i = 0; i < TM; ++i) {
    int gr = row0 + tr + i;
    if (gr >= N) continue;
#pragma unroll
    for (int j = 0; j < TN; ++j) {
      int gc = col0 + tc + j;
      if (gc >= M) continue;
      float v = acc[i][j];
      if (EPI >= 1) v += bias[gc];
      if (EPI == 2) v = fmaxf(v, 0.f);
      C[(long long)gr * M + gc] = v;
    }
  }
}

// ---------------- GATv2 ----------------

__global__ void gat_logits_kernel(const float* __restrict__ xl, const float* __restrict__ xr,
                                  const float* __restrict__ att, const int* __restrict__ ei,
                                  float* __restrict__ ea, int E, int N) {
  const long long total = (long long)(E + N) * HEADS;
  long long i = (long long)blockIdx.x * blockDim.x + threadIdx.x;
  long long stride = (long long)gridDim.x * blockDim.x;
  for (; i < total; i += stride) {
    int e = (int)(i >> 2);
    int hh = (int)(i & 3);
    int s, t;
    if (e < E) { s = ei[e]; t = ei[E + e]; } else { s = t = e - E; }
    const float* pl = xl + (long long)s * 128 + hh * 32;
    const float* pr = xr + (long long)t * 128 + hh * 32;
    const float* pa = att + hh * 32;
    float acc = 0.f;
#pragma unroll
    for (int c = 0; c < 32; ++c) {
      float v = pl[c] + pr[c];
      v = v >= 0.f ? v : 0.2f * v;
      acc += v * pa[c];
    }
    ea[i] = acc;
  }
}

// wave per node: per-head max, exp, sum; writes CSR-ordered unnormalized
// weights + per-node 1/sum. No atomics, fully deterministic.
__global__ __launch_bounds__(256) void gat_norm_kernel(
    const int* __restrict__ rowptr, const int* __restrict__ eids,
    const float* __restrict__ ea, float* __restrict__ wvals,
    float* __restrict__ selfw, float* __restrict__ suminv, int E, int N) {
  const int node = blockIdx.x * 4 + (threadIdx.x >> 6);
  if (node >= N) return;
  const int lane = threadIdx.x & 63;
  const int h = lane & 3;
  const int start = rowptr[node];
  const int cnt = rowptr[node + 1] - start;
  const int items = (cnt + 1) * 4;  // + self entry

  float m = -1e30f;
  for (int it = lane; it < items; it += 64) {
    int idx = it >> 2;
    int eid = (idx < cnt) ? eids[start + idx] : (E + node);
    m = fmaxf(m, ea[(long long)eid * 4 + h]);
  }
#pragma unroll
  for (int off = 4; off < 64; off <<= 1) m = fmaxf(m, __shfl_xor(m, off));

  float s = 0.f;
  for (int it = lane; it < items; it += 64) {
    int idx = it >> 2;
    int eid = (idx < cnt) ? eids[start + idx] : (E + node);
    float p = __expf(ea[(long long)eid * 4 + h] - m);
    s += p;
    if (idx < cnt) wvals[(long long)(start + idx) * 4 + h] = p;
    else           selfw[(long long)node * 4 + h] = p;
  }
#pragma unroll
  for (int off = 4; off < 64; off <<= 1) s += __shfl_xor(s, off);
  if (lane < 4) suminv[(long long)node * 4 + lane] = 1.0f / (s + 1e-16f);
}

// out[node] = relu( suminv * (sum_j w_j * xl[col_j] + selfw * xl[node]) + bg )
__global__ __launch_bounds__(256) void gat_gather_kernel(
    const float4* __restrict__ xl, const int* __restrict__ rowptr,
    const int* __restrict__ cols, const float* __restrict__ wvals,
    const float* __restrict__ selfw, const float* __restrict__ suminv,
    const float* __restrict__ bg, float4* __restrict__ out, int N) {
  const int node = blockIdx.x * 8 + threadIdx.x / 32;
  const int q = threadIdx.x % 32;   // float4 index in 128-dim row
  if (node >= N) return;
  const int h = q >> 3;
  const int start = rowptr[node], end = rowptr[node + 1];
  float4 acc = make_float4(0.f, 0.f, 0.f, 0.f);
  for (int j = start; j < end; ++j) {
    float w = wvals[(long long)j * 4 + h];
    float4 v = xl[(long long)cols[j] * 32 + q];
    acc.x += w * v.x; acc.y += w * v.y; acc.z += w * v.z; acc.w += w * v.w;
  }
  {
    float w = selfw[(long long)node * 4 + h];
    float4 v = xl[(long long)node * 32 + q];
    acc.x += w * v.x; acc.y += w * v.y; acc.z += w * v.z; acc.w += w * v.w;
  }
  const float inv = suminv[(long long)node * 4 + h];
  float4 b = ((const float4*)bg)[q];
  float4 r;
  r.x = fmaxf(acc.x * inv + b.x, 0.f);
  r.y = fmaxf(acc.y * inv + b.y, 0.f);
  r.z = fmaxf(acc.z * inv + b.z, 0.f);
  r.w = fmaxf(acc.w * inv + b.w, 0.f);
  out[(long long)node * 32 + q] = r;
}

// out = relu(c1*h + c2*t)
__global__ void combine_relu_kernel(const float* h, const float* t, float* out,
                                    float c1, float c2, long long n) {
  long long i = (long long)blockIdx.x * blockDim.x + threadIdx.x;
  long long stride = (long long)gridDim.x * blockDim.x;
  for (; i < n; i += stride) out[i] = fmaxf(c1 * h[i] + c2 * t[i], 0.f);
}

// ---------------------------------------------------------------------------

extern "C" void kernel_launch(void* const* d_in, const int* in_sizes, int n_in,
                              void* d_out, int out_size, void* d_ws, size_t ws_size,
                              hipStream_t stream) {
  const float* x  = (const float*)d_in[0];
  const int*   ei = (const int*)d_in[1];   // int32 (harness materializes ints as int32)
  const float* W1 = (const float*)d_in[2];  const float* b1 = (const float*)d_in[3];
  const float* W2 = (const float*)d_in[4];  const float* b2 = (const float*)d_in[5];
  const float* W3 = (const float*)d_in[6];  const float* b3 = (const float*)d_in[7];
  const float* W4 = (const float*)d_in[8];  const float* b4 = (const float*)d_in[9];
  const float* Wl = (const float*)d_in[10]; const float* Wr = (const float*)d_in[11];
  const float* att= (const float*)d_in[12]; const float* bg = (const float*)d_in[13];
  const float* Wc1= (const float*)d_in[14];
  const float* W5 = (const float*)d_in[15]; const float* b5 = (const float*)d_in[16];
  const float* Wc2= (const float*)d_in[17];
  const float* Wo = (const float*)d_in[18]; const float* bo = (const float*)d_in[19];

  const int N = in_sizes[0] / 300;
  const int E = in_sizes[1] / 2;
  float* out = (float*)d_out;

  const float BETA = 0.04879016416943205f;  // log(0.1/2 + 1)
  const float OMB  = 1.0f - BETA;

  // ---- workspace carve-up (16B-aligned chunks) ----
  float* wsf = (float*)d_ws;
  auto alloc = [&](long long nelem) {
    float* p = wsf; wsf += (nelem + 3) & ~3LL; return p;
  };
  float* dinv   = alloc(N);
  int*   rowptr = (int*)alloc(N + 1);
  int*   cols   = (int*)alloc(E);
  int*   eids   = (int*)alloc(E);
  float* vals   = alloc(E);
  float* x1     = alloc((long long)N * 256);
  float* x2     = alloc((long long)N * 128);
  float* bufA   = alloc((long long)N * 256);
  float* bufB   = alloc((long long)N * 256);
  float* bufC   = alloc((long long)N * 256);
  float* ea     = alloc((long long)(E + N) * HEADS);
  float* selfw  = alloc((long long)N * HEADS);
  float* suminv = alloc((long long)N * HEADS);
  int*   bsum   = (int*)alloc(64);
  // setup-only overlaps (dead regions at time of use):
  int*   deg  = (int*)ea;        // used before ea exists
  int*   fill = (int*)(ea + N);  // used before ea exists
  float* wvals = bufC;           // used after xr (bufC) is dead, before next gemm

  auto gemm = [&](const float* A, const float* Wm, const float* bias, float* C,
                  int n, int K, int M, int epi) {
    dim3 grid((M + 63) / 64, (n + 63) / 64);
    if (epi == 0) gemm_kernel<0><<<grid, 256, 0, stream>>>(A, Wm, bias, C, n, K, M);
    else          gemm_kernel<2><<<grid, 256, 0, stream>>>(A, Wm, bias, C, n, K, M);
  };
  auto prop = [&](const float* src, float* dst, int D, int epi, const float* bx) {
    int tpn = D / 4, npb = 256 / tpn;
    int grid = (N + npb - 1) / npb;
    const float4* s4 = (const float4*)src;
    float4* d4 = (float4*)dst;
#define PROP_CASE(DD, EE) \
    if (D == DD && epi == EE) { prop_csr_kernel<DD, EE><<<grid, 256, 0, stream>>>(s4, rowptr, cols, vals, dinv, bx, d4, N); return; }
    PROP_CASE(256, 0) PROP_CASE(256, 1) PROP_CASE(256, 2) PROP_CASE(256, 3)
    PROP_CASE(128, 0) PROP_CASE(128, 1) PROP_CASE(128, 2) PROP_CASE(128, 3)
    PROP_CASE(64, 2)  PROP_CASE(32, 2)
#undef PROP_CASE
  };

  // ---- CSR build ----
  hipMemsetAsync(deg, 0, (size_t)N * sizeof(int), stream);
  hipMemsetAsync(fill, 0, (size_t)N * sizeof(int), stream);
  hipMemsetAsync(rowptr, 0, sizeof(int), stream);
  deg_kernel<<<2048, 256, 0, stream>>>(ei, deg, E);
  dinv_kernel<<<(N + 255) / 256, 256, 0, stream>>>(deg, dinv, N);
  {
    int nb = (N + 2047) / 2048;
    scan_block_kernel<<<nb, 256, 0, stream>>>(deg, rowptr + 1, bsum, N);
    scan_small_kernel<<<1, 64, 0, stream>>>(bsum, nb);
    scan_add_kernel<<<nb, 256, 0, stream>>>(rowptr + 1, bsum, N);
  }
  fill_csr_kernel<<<2048, 256, 0, stream>>>(ei, dinv, rowptr, fill, cols, eids, vals, E);

  // ---- layer 1: x1 = relu(prop(x@W1)+b1) ----
  gemm(x, W1, nullptr, bufA, N, 300, 256, 0);
  prop(bufA, x1, 256, 2, b1);

  // ---- layer 2: x2 = relu(prop(x1@W2)+b2) ----
  gemm(x1, W2, nullptr, bufA, N, 256, 128, 0);
  prop(bufA, x2, 128, 2, b2);

  // ---- layer 3: relu(prop(x2@W3)+b3) ----
  gemm(x2, W3, nullptr, bufA, N, 128, 64, 0);
  prop(bufA, bufB, 64, 2, b3);

  // ---- layer 4: relu(prop(.@W4)+b4) ----
  gemm(bufB, W4, nullptr, bufA, N, 64, 32, 0);
  prop(bufA, bufB, 32, 2, b4);   // cur (N x 32) in bufB

  // ---- GATv2 ----
  gemm(bufB, Wl, nullptr, bufA, N, 32, 128, 0);  // xl in bufA
  gemm(bufB, Wr, nullptr, bufC, N, 32, 128, 0);  // xr in bufC
  gat_logits_kernel<<<4096, 256, 0, stream>>>(bufA, bufC, att, ei, ea, E, N);
  gat_norm_kernel<<<(N + 3) / 4, 256, 0, stream>>>(rowptr, eids, ea, wvals, selfw, suminv, E, N);
  gat_gather_kernel<<<(N + 7) / 8, 256, 0, stream>>>((const float4*)bufA, rowptr, cols, wvals,
                                                     selfw, suminv, bg, (float4*)bufB, N);
  // x3 (N x 128) in bufB

  // ---- GCN2 #1: relu((1-B)*h + B*(h@Wc1)), h = 0.5*prop(x3) + 0.5*x2 ----
  prop(bufB, bufA, 128, 3, x2);                   // h in bufA
  gemm(bufA, Wc1, nullptr, bufC, N, 128, 128, 0);
  combine_relu_kernel<<<4096, 256, 0, stream>>>(bufA, bufC, bufA, OMB, BETA, (long long)N * 128);
  // result (N x 128) in bufA

  // ---- W5 layer: relu(prop(x@W5)+b5) == relu(prop(x)@W5+b5) ----
  prop(bufA, bufB, 128, 0, nullptr);
  gemm(bufB, W5, b5, bufC, N, 128, 256, 2);       // (N x 256) in bufC

  // ---- GCN2 #2: h = 0.5*prop(.)+0.5*x1 ----
  prop(bufC, bufA, 256, 3, x1);                   // h in bufA
  gemm(bufA, Wc2, nullptr, bufB, N, 256, 256, 0);
  combine_relu_kernel<<<4096, 256, 0, stream>>>(bufA, bufB, bufB, OMB, BETA, (long long)N * 256);
  // result (N x 256) in bufB

  // ---- final: prop(x@Wo) + bo ----
  gemm(bufB, Wo, nullptr, bufA, N, 256, 128, 0);
  prop(bufA, out, 128, 1, bo);
}

// Round 5
// 1502.861 us; speedup vs baseline: 3.2015x; 1.2965x over previous
//
#include <hip/hip_runtime.h>
#include <math.h>

// ---------------------------------------------------------------------------
// GraphAutoEncoder forward on MI355X. Round 4 = round 3 (MFMA split-bf16
// GEMMs) with workspace shrunk below the proven-safe ~257MB:
//   - bufC eliminated (buffer choreography reuses dead buffers)
//   - ea/wvals/deg/fill overlaid on the Ahi/Alo bf16 planes (dead intervals)
//   - static LDS in the MFMA GEMM (no dynamic-shared launch risk)
// ---------------------------------------------------------------------------

static constexpr int HEADS = 4;

typedef __attribute__((ext_vector_type(8))) short short8;
typedef __attribute__((ext_vector_type(4))) float f32x4;

__device__ __forceinline__ unsigned short f32_to_bf16(float x) {
  unsigned int u = __float_as_uint(x);
  u = (u + 0x7FFF + ((u >> 16) & 1)) >> 16;   // RNE
  return (unsigned short)u;
}
__device__ __forceinline__ float bf16_to_f32(unsigned short h) {
  return __uint_as_float(((unsigned int)h) << 16);
}

// ---------------- CSR build ----------------

__global__ void deg_kernel(const int* __restrict__ ei, int* __restrict__ deg, int E) {
  int i = blockIdx.x * blockDim.x + threadIdx.x;
  int stride = gridDim.x * blockDim.x;
  for (; i < E; i += stride) atomicAdd(&deg[ei[E + i]], 1);
}

__global__ void dinv_kernel(const int* __restrict__ deg, float* __restrict__ dinv, int N) {
  int i = blockIdx.x * blockDim.x + threadIdx.x;
  if (i < N) dinv[i] = rsqrtf((float)(deg[i] + 1));  // +1 self-loop
}

__global__ __launch_bounds__(256) void scan_block_kernel(const int* __restrict__ in,
                                                         int* __restrict__ out,
                                                         int* __restrict__ bsum, int n) {
  __shared__ int lds[256];
  const int base = blockIdx.x * 2048;
  const int tid = threadIdx.x;
  int v[8];
  int s = 0;
#pragma unroll
  for (int k = 0; k < 8; ++k) {
    int idx = base + tid * 8 + k;
    v[k] = (idx < n) ? in[idx] : 0;
    s += v[k];
  }
  lds[tid] = s;
  __syncthreads();
  for (int off = 1; off < 256; off <<= 1) {
    int t = (tid >= off) ? lds[tid - off] : 0;
    __syncthreads();
    lds[tid] += t;
    __syncthreads();
  }
  int run = (tid > 0) ? lds[tid - 1] : 0;
#pragma unroll
  for (int k = 0; k < 8; ++k) {
    int idx = base + tid * 8 + k;
    run += v[k];
    if (idx < n) out[idx] = run;
  }
  if (tid == 255) bsum[blockIdx.x] = lds[255];
}

__global__ void scan_small_kernel(int* bsum, int nb) {
  if (threadIdx.x == 0 && blockIdx.x == 0) {
    int run = 0;
    for (int i = 0; i < nb; ++i) { int t = bsum[i]; bsum[i] = run; run += t; }
  }
}

__global__ __launch_bounds__(256) void scan_add_kernel(int* __restrict__ out,
                                                       const int* __restrict__ bsum, int n) {
  int idx = blockIdx.x * 2048 + threadIdx.x;
  const int add = bsum[blockIdx.x];
#pragma unroll
  for (int k = 0; k < 8; ++k, idx += 256)
    if (idx < n) out[idx] += add;
}

__global__ void fill_csr_kernel(const int* __restrict__ ei, const float* __restrict__ dinv,
                                const int* __restrict__ rowptr, int* __restrict__ fill,
                                int* __restrict__ cols, int* __restrict__ eids,
                                float* __restrict__ vals, int E) {
  int e = blockIdx.x * blockDim.x + threadIdx.x;
  int stride = gridDim.x * blockDim.x;
  for (; e < E; e += stride) {
    int s = ei[e], t = ei[E + e];
    int pos = rowptr[t] + atomicAdd(&fill[t], 1);
    cols[pos] = s;
    eids[pos] = e;
    vals[pos] = dinv[s] * dinv[t];
  }
}

// ---------------- propagation (CSR gather, float4) ----------------
// EPI: 0 none | 1 +bias | 2 relu(+bias) | 3 0.5*acc+0.5*x0
template <int D, int EPI>
__global__ __launch_bounds__(256) void prop_csr_kernel(
    const float4* __restrict__ h, const int* __restrict__ rowptr,
    const int* __restrict__ cols, const float* __restrict__ vals,
    const float* __restrict__ dinv, const float* __restrict__ bx,
    float4* __restrict__ out, int N) {
  constexpr int TPN = D / 4;
  constexpr int NPB = 256 / TPN;
  const int node = blockIdx.x * NPB + threadIdx.x / TPN;
  const int q = threadIdx.x % TPN;
  if (node >= N) return;
  const int start = rowptr[node], end = rowptr[node + 1];
  float4 acc = make_float4(0.f, 0.f, 0.f, 0.f);
  int j = start;
  for (; j + 1 < end; j += 2) {
    float v0 = vals[j], v1 = vals[j + 1];
    float4 a = h[(long long)cols[j] * TPN + q];
    float4 b = h[(long long)cols[j + 1] * TPN + q];
    acc.x += v0 * a.x + v1 * b.x;
    acc.y += v0 * a.y + v1 * b.y;
    acc.z += v0 * a.z + v1 * b.z;
    acc.w += v0 * a.w + v1 * b.w;
  }
  if (j < end) {
    float v = vals[j];
    float4 a = h[(long long)cols[j] * TPN + q];
    acc.x += v * a.x; acc.y += v * a.y; acc.z += v * a.z; acc.w += v * a.w;
  }
  {
    float di = dinv[node];
    float sv = di * di;
    float4 a = h[(long long)node * TPN + q];
    acc.x += sv * a.x; acc.y += sv * a.y; acc.z += sv * a.z; acc.w += sv * a.w;
  }
  float4 r;
  if (EPI == 0) {
    r = acc;
  } else if (EPI == 1 || EPI == 2) {
    float4 b = ((const float4*)bx)[q];
    r.x = acc.x + b.x; r.y = acc.y + b.y; r.z = acc.z + b.z; r.w = acc.w + b.w;
    if (EPI == 2) {
      r.x = fmaxf(r.x, 0.f); r.y = fmaxf(r.y, 0.f);
      r.z = fmaxf(r.z, 0.f); r.w = fmaxf(r.w, 0.f);
    }
  } else {
    float4 x0 = ((const float4*)bx)[(long long)node * TPN + q];
    r.x = 0.5f * (acc.x + x0.x); r.y = 0.5f * (acc.y + x0.y);
    r.z = 0.5f * (acc.z + x0.z); r.w = 0.5f * (acc.w + x0.w);
  }
  out[(long long)node * TPN + q] = r;
}

// ---------------- split-bf16 conversion ----------------
__global__ void conv_hilo_kernel(const float* __restrict__ in, unsigned short* __restrict__ hi,
                                 unsigned short* __restrict__ lo, int N, int K, int Kp) {
  const long long total = (long long)N * (Kp / 4);
  long long i = (long long)blockIdx.x * blockDim.x + threadIdx.x;
  const long long stride = (long long)gridDim.x * blockDim.x;
  const int q = Kp / 4;
  for (; i < total; i += stride) {
    int r = (int)(i / q);
    int col = (int)(i % q) * 4;
    ushort4 h4 = make_ushort4(0, 0, 0, 0), l4 = make_ushort4(0, 0, 0, 0);
    if (col < K) {
      float4 v = *(const float4*)(in + (long long)r * K + col);
      h4.x = f32_to_bf16(v.x); l4.x = f32_to_bf16(v.x - bf16_to_f32(h4.x));
      h4.y = f32_to_bf16(v.y); l4.y = f32_to_bf16(v.y - bf16_to_f32(h4.y));
      h4.z = f32_to_bf16(v.z); l4.z = f32_to_bf16(v.z - bf16_to_f32(h4.z));
      h4.w = f32_to_bf16(v.w); l4.w = f32_to_bf16(v.w - bf16_to_f32(h4.w));
    }
    *(ushort4*)(hi + (long long)r * Kp + col) = h4;
    *(ushort4*)(lo + (long long)r * Kp + col) = l4;
  }
}

// ---------------- weight packing (fragment order) ----------------
// lane l holds B[k = 64*chunk + 32*s + 8*(l>>4) + j][col = 16*t + (l&15)]
__global__ void pack_w_kernel(const float* __restrict__ W, unsigned short* __restrict__ hi,
                              unsigned short* __restrict__ lo, int K, int M) {
  int i = blockIdx.x * blockDim.x + threadIdx.x;
  int stride = gridDim.x * blockDim.x;
  const int MT = M >> 4;
  for (; i < K * M; i += stride) {
    int k = i / M, m = i % M;
    float v = W[i];
    unsigned short h = f32_to_bf16(v);
    unsigned short l = f32_to_bf16(v - bf16_to_f32(h));
    int chunk = k >> 6, kin = k & 63;
    int s = (kin >> 5) & 1, kin2 = kin & 31;
    int lane = ((kin2 >> 3) << 4) | (m & 15);
    int j = kin2 & 7, t = m >> 4;
    long long idx = ((((long long)(chunk * MT + t) * 2 + s) * 64 + lane) * 8 + j);
    hi[idx] = h;
    lo[idx] = l;
  }
}

// ---------------- MFMA GEMM (split-bf16, 3 products) ----------------
// C[N x M] = A[N x Kp] @ W[Kp x M]; block = 4 waves x 32 rows, full M.
template <int MT, int EPI>
__global__ __launch_bounds__(256) void gemm_mfma_kernel(
    const unsigned short* __restrict__ Ahi, const unsigned short* __restrict__ Alo,
    const unsigned short* __restrict__ Phi, const unsigned short* __restrict__ Plo,
    const float* __restrict__ bias, float* __restrict__ C, int N, int Kp) {
  constexpr int M = MT * 16;
  constexpr int chunk_elems = M * 64;
  __shared__ unsigned short lds[2 * chunk_elems];  // hi plane + lo plane
  const int tid = threadIdx.x;
  const int w = tid >> 6, l = tid & 63;
  const int lr = l & 15, lh = l >> 4;
  const int rowbase = blockIdx.x * 128 + w * 32;
  int r0 = rowbase + lr;      if (r0 >= N) r0 = N - 1;
  int r1 = rowbase + 16 + lr; if (r1 >= N) r1 = N - 1;

  f32x4 acc[2][MT] = {};
  unsigned short* ldsHi = lds;
  unsigned short* ldsLo = lds + chunk_elems;
  const int nchunks = Kp >> 6;
  const int n16 = chunk_elems / 8;  // uint4 slots per plane

  for (int c = 0; c < nchunks; ++c) {
    const uint4* srcH = (const uint4*)(Phi + (long long)c * chunk_elems);
    const uint4* srcL = (const uint4*)(Plo + (long long)c * chunk_elems);
    uint4* dH = (uint4*)ldsHi;
    uint4* dL = (uint4*)ldsLo;
    __syncthreads();
    for (int i = tid; i < n16; i += 256) { dH[i] = srcH[i]; dL[i] = srcL[i]; }
    __syncthreads();
#pragma unroll
    for (int s = 0; s < 2; ++s) {
      const long long abase = (long long)c * 64 + s * 32 + lh * 8;
      short8 a0h = *(const short8*)(Ahi + (long long)r0 * Kp + abase);
      short8 a0l = *(const short8*)(Alo + (long long)r0 * Kp + abase);
      short8 a1h = *(const short8*)(Ahi + (long long)r1 * Kp + abase);
      short8 a1l = *(const short8*)(Alo + (long long)r1 * Kp + abase);
#pragma unroll
      for (int t = 0; t < MT; ++t) {
        const int boff = ((t * 2 + s) * 64 + l) * 8;
        short8 bh = *(const short8*)(ldsHi + boff);
        short8 bl = *(const short8*)(ldsLo + boff);
        acc[0][t] = __builtin_amdgcn_mfma_f32_16x16x32_bf16(a0h, bh, acc[0][t], 0, 0, 0);
        acc[0][t] = __builtin_amdgcn_mfma_f32_16x16x32_bf16(a0h, bl, acc[0][t], 0, 0, 0);
        acc[0][t] = __builtin_amdgcn_mfma_f32_16x16x32_bf16(a0l, bh, acc[0][t], 0, 0, 0);
        acc[1][t] = __builtin_amdgcn_mfma_f32_16x16x32_bf16(a1h, bh, acc[1][t], 0, 0, 0);
        acc[1][t] = __builtin_amdgcn_mfma_f32_16x16x32_bf16(a1h, bl, acc[1][t], 0, 0, 0);
        acc[1][t] = __builtin_amdgcn_mfma_f32_16x16x32_bf16(a1l, bh, acc[1][t], 0, 0, 0);
      }
    }
  }
  // epilogue: row = rowbase + rt*16 + lh*4 + j, col = t*16 + lr  (m89 layout)
#pragma unroll
  for (int rt = 0; rt < 2; ++rt) {
#pragma unroll
    for (int t = 0; t < MT; ++t) {
      const int col = t * 16 + lr;
      float b = (EPI >= 1) ? bias[col] : 0.f;
#pragma unroll
      for (int j = 0; j < 4; ++j) {
        int row = rowbase + rt * 16 + lh * 4 + j;
        if (row < N) {
          float v = acc[rt][t][j] + b;
          if (EPI == 2) v = fmaxf(v, 0.f);
          C[(long long)row * M + col] = v;
        }
      }
    }
  }
}

// ---------------- GATv2 ----------------

__global__ void gat_logits_kernel(const float* __restrict__ xl, const float* __restrict__ xr,
                                  const float* __restrict__ att, const int* __restrict__ ei,
                                  float* __restrict__ ea, int E, int N) {
  const long long total = (long long)(E + N) * HEADS;
  long long i = (long long)blockIdx.x * blockDim.x + threadIdx.x;
  long long stride = (long long)gridDim.x * blockDim.x;
  for (; i < total; i += stride) {
    int e = (int)(i >> 2);
    int hh = (int)(i & 3);
    int s, t;
    if (e < E) { s = ei[e]; t = ei[E + e]; } else { s = t = e - E; }
    const float* pl = xl + (long long)s * 128 + hh * 32;
    const float* pr = xr + (long long)t * 128 + hh * 32;
    const float* pa = att + hh * 32;
    float acc = 0.f;
#pragma unroll
    for (int c = 0; c < 32; ++c) {
      float v = pl[c] + pr[c];
      v = v >= 0.f ? v : 0.2f * v;
      acc += v * pa[c];
    }
    ea[i] = acc;
  }
}

__global__ __launch_bounds__(256) void gat_norm_kernel(
    const int* __restrict__ rowptr, const int* __restrict__ eids,
    const float* __restrict__ ea, float* __restrict__ wvals,
    float* __restrict__ selfw, float* __restrict__ suminv, int E, int N) {
  const int node = blockIdx.x * 4 + (threadIdx.x >> 6);
  if (node >= N) return;
  const int lane = threadIdx.x & 63;
  const int h = lane & 3;
  const int start = rowptr[node];
  const int cnt = rowptr[node + 1] - start;
  const int items = (cnt + 1) * 4;

  float m = -1e30f;
  for (int it = lane; it < items; it += 64) {
    int idx = it >> 2;
    int eid = (idx < cnt) ? eids[start + idx] : (E + node);
    m = fmaxf(m, ea[(long long)eid * 4 + h]);
  }
#pragma unroll
  for (int off = 4; off < 64; off <<= 1) m = fmaxf(m, __shfl_xor(m, off));

  float s = 0.f;
  for (int it = lane; it < items; it += 64) {
    int idx = it >> 2;
    int eid = (idx < cnt) ? eids[start + idx] : (E + node);
    float p = __expf(ea[(long long)eid * 4 + h] - m);
    s += p;
    if (idx < cnt) wvals[(long long)(start + idx) * 4 + h] = p;
    else           selfw[(long long)node * 4 + h] = p;
  }
#pragma unroll
  for (int off = 4; off < 64; off <<= 1) s += __shfl_xor(s, off);
  if (lane < 4) suminv[(long long)node * 4 + lane] = 1.0f / (s + 1e-16f);
}

__global__ __launch_bounds__(256) void gat_gather_kernel(
    const float4* __restrict__ xl, const int* __restrict__ rowptr,
    const int* __restrict__ cols, const float* __restrict__ wvals,
    const float* __restrict__ selfw, const float* __restrict__ suminv,
    const float* __restrict__ bg, float4* __restrict__ out, int N) {
  const int node = blockIdx.x * 8 + threadIdx.x / 32;
  const int q = threadIdx.x % 32;
  if (node >= N) return;
  const int h = q >> 3;
  const int start = rowptr[node], end = rowptr[node + 1];
  float4 acc = make_float4(0.f, 0.f, 0.f, 0.f);
  for (int j = start; j < end; ++j) {
    float w = wvals[(long long)j * 4 + h];
    float4 v = xl[(long long)cols[j] * 32 + q];
    acc.x += w * v.x; acc.y += w * v.y; acc.z += w * v.z; acc.w += w * v.w;
  }
  {
    float w = selfw[(long long)node * 4 + h];
    float4 v = xl[(long long)node * 32 + q];
    acc.x += w * v.x; acc.y += w * v.y; acc.z += w * v.z; acc.w += w * v.w;
  }
  const float inv = suminv[(long long)node * 4 + h];
  float4 b = ((const float4*)bg)[q];
  float4 r;
  r.x = fmaxf(acc.x * inv + b.x, 0.f);
  r.y = fmaxf(acc.y * inv + b.y, 0.f);
  r.z = fmaxf(acc.z * inv + b.z, 0.f);
  r.w = fmaxf(acc.w * inv + b.w, 0.f);
  out[(long long)node * 32 + q] = r;
}

__global__ void combine_relu_kernel(const float* h, const float* t, float* out,
                                    float c1, float c2, long long n) {
  long long i = (long long)blockIdx.x * blockDim.x + threadIdx.x;
  long long stride = (long long)gridDim.x * blockDim.x;
  for (; i < n; i += stride) out[i] = fmaxf(c1 * h[i] + c2 * t[i], 0.f);
}

// ---------------------------------------------------------------------------

extern "C" void kernel_launch(void* const* d_in, const int* in_sizes, int n_in,
                              void* d_out, int out_size, void* d_ws, size_t ws_size,
                              hipStream_t stream) {
  const float* x  = (const float*)d_in[0];
  const int*   ei = (const int*)d_in[1];
  const float* W1 = (const float*)d_in[2];  const float* b1 = (const float*)d_in[3];
  const float* W2 = (const float*)d_in[4];  const float* b2 = (const float*)d_in[5];
  const float* W3 = (const float*)d_in[6];  const float* b3 = (const float*)d_in[7];
  const float* W4 = (const float*)d_in[8];  const float* b4 = (const float*)d_in[9];
  const float* Wl = (const float*)d_in[10]; const float* Wr = (const float*)d_in[11];
  const float* att= (const float*)d_in[12]; const float* bg = (const float*)d_in[13];
  const float* Wc1= (const float*)d_in[14];
  const float* W5 = (const float*)d_in[15]; const float* b5 = (const float*)d_in[16];
  const float* Wc2= (const float*)d_in[17];
  const float* Wo = (const float*)d_in[18]; const float* bo = (const float*)d_in[19];

  const int N = in_sizes[0] / 300;
  const int E = in_sizes[1] / 2;
  float* out = (float*)d_out;

  const float BETA = 0.04879016416943205f;
  const float OMB  = 1.0f - BETA;

  // ---- workspace carve-up (total ~244 MiB; round 2's ~257MB footprint passed) ----
  float* wsf = (float*)d_ws;
  auto alloc = [&](long long nelem) {
    float* p = wsf; wsf += (nelem + 3) & ~3LL; return p;
  };
  float* dinv   = alloc(N);
  int*   rowptr = (int*)alloc(N + 1);
  int*   cols   = (int*)alloc(E);
  int*   eids   = (int*)alloc(E);
  float* vals   = alloc(E);
  float* x1     = alloc((long long)N * 256);
  float* x2     = alloc((long long)N * 128);
  float* bufA   = alloc((long long)N * 256);
  float* bufB   = alloc((long long)N * 256);
  float* selfw  = alloc((long long)N * HEADS);
  float* suminv = alloc((long long)N * HEADS);
  int*   bsum   = (int*)alloc(64);
  unsigned short* Ahi = (unsigned short*)alloc((long long)N * 160);  // N*320 ushorts
  unsigned short* Alo = (unsigned short*)alloc((long long)N * 160);
  // packed weight arena
  struct WDesc { const float* W; int K, M; };
  WDesc wd[10] = {{W1,300,256},{W2,256,128},{W3,128,64},{W4,64,32},{Wl,32,128},
                  {Wr,32,128},{Wc1,128,128},{W5,128,256},{Wc2,256,256},{Wo,256,128}};
  long long woff[10], wtot = 0;
  int wkp[10];
  for (int i = 0; i < 10; ++i) {
    wkp[i] = (wd[i].K + 63) & ~63;
    woff[i] = wtot;
    wtot += 2LL * wkp[i] * wd[i].M;
  }
  unsigned short* warena = (unsigned short*)alloc(wtot / 2 + 4);
  // overlays on Ahi/Alo dead intervals:
  int*   deg   = (int*)Ahi;        // CSR build runs before first convA
  int*   fill  = (int*)Alo;
  float* ea    = (float*)Alo;      // GAT: after gemm(xr), before next convA
  float* wvals = (float*)Ahi;      //   (E+N)*4 = 3.4M floats < 8M-float plane

  auto convA = [&](const float* src, int K, int Kp) {
    long long total = (long long)N * (Kp / 4);
    int blocks = (int)(((total + 255) / 256 < 4096) ? (total + 255) / 256 : 4096);
    conv_hilo_kernel<<<blocks, 256, 0, stream>>>(src, Ahi, Alo, N, K, Kp);
  };
  const int gemm_grid = (N + 127) / 128;
  auto gemm = [&](int wi, const float* bias, float* C, int MT, int epi) {
    const unsigned short* Phi = warena + woff[wi];
    const unsigned short* Plo = Phi + (long long)wkp[wi] * wd[wi].M;
    if (MT == 16 && epi == 0)
      gemm_mfma_kernel<16,0><<<gemm_grid, 256, 0, stream>>>(Ahi, Alo, Phi, Plo, bias, C, N, wkp[wi]);
    else if (MT == 16 && epi == 2)
      gemm_mfma_kernel<16,2><<<gemm_grid, 256, 0, stream>>>(Ahi, Alo, Phi, Plo, bias, C, N, wkp[wi]);
    else if (MT == 8)
      gemm_mfma_kernel<8,0><<<gemm_grid, 256, 0, stream>>>(Ahi, Alo, Phi, Plo, bias, C, N, wkp[wi]);
    else if (MT == 4)
      gemm_mfma_kernel<4,0><<<gemm_grid, 256, 0, stream>>>(Ahi, Alo, Phi, Plo, bias, C, N, wkp[wi]);
    else
      gemm_mfma_kernel<2,0><<<gemm_grid, 256, 0, stream>>>(Ahi, Alo, Phi, Plo, bias, C, N, wkp[wi]);
  };
  auto prop = [&](const float* src, float* dst, int D, int epi, const float* bx) {
    int tpn = D / 4, npb = 256 / tpn;
    int grid = (N + npb - 1) / npb;
    const float4* s4 = (const float4*)src;
    float4* d4 = (float4*)dst;
#define PROP_CASE(DD, EE) \
    if (D == DD && epi == EE) { prop_csr_kernel<DD, EE><<<grid, 256, 0, stream>>>(s4, rowptr, cols, vals, dinv, bx, d4, N); return; }
    PROP_CASE(256, 0) PROP_CASE(256, 1) PROP_CASE(256, 2) PROP_CASE(256, 3)
    PROP_CASE(128, 0) PROP_CASE(128, 1) PROP_CASE(128, 2) PROP_CASE(128, 3)
    PROP_CASE(64, 2)  PROP_CASE(32, 2)
#undef PROP_CASE
  };

  // ---- weight packing (once per launch) ----
  hipMemsetAsync(warena, 0, (size_t)wtot * sizeof(unsigned short), stream);
  for (int i = 0; i < 10; ++i) {
    unsigned short* Phi = warena + woff[i];
    unsigned short* Plo = Phi + (long long)wkp[i] * wd[i].M;
    int total = wd[i].K * wd[i].M;
    pack_w_kernel<<<(total + 255) / 256, 256, 0, stream>>>(wd[i].W, Phi, Plo, wd[i].K, wd[i].M);
  }

  // ---- CSR build (deg/fill overlay Ahi/Alo; done before first convA) ----
  hipMemsetAsync(deg, 0, (size_t)N * sizeof(int), stream);
  hipMemsetAsync(fill, 0, (size_t)N * sizeof(int), stream);
  hipMemsetAsync(rowptr, 0, sizeof(int), stream);
  deg_kernel<<<2048, 256, 0, stream>>>(ei, deg, E);
  dinv_kernel<<<(N + 255) / 256, 256, 0, stream>>>(deg, dinv, N);
  {
    int nb = (N + 2047) / 2048;
    scan_block_kernel<<<nb, 256, 0, stream>>>(deg, rowptr + 1, bsum, N);
    scan_small_kernel<<<1, 64, 0, stream>>>(bsum, nb);
    scan_add_kernel<<<nb, 256, 0, stream>>>(rowptr + 1, bsum, N);
  }
  fill_csr_kernel<<<2048, 256, 0, stream>>>(ei, dinv, rowptr, fill, cols, eids, vals, E);

  // ---- layer 1: x1 = relu(prop(x@W1)+b1) ----
  convA(x, 300, 320);
  gemm(0, nullptr, bufA, 16, 0);
  prop(bufA, x1, 256, 2, b1);

  // ---- layer 2 ----
  convA(x1, 256, 256);
  gemm(1, nullptr, bufA, 8, 0);
  prop(bufA, x2, 128, 2, b2);

  // ---- layer 3 ----
  convA(x2, 128, 128);
  gemm(2, nullptr, bufA, 4, 0);
  prop(bufA, bufB, 64, 2, b3);

  // ---- layer 4 ----
  convA(bufB, 64, 64);
  gemm(3, nullptr, bufA, 2, 0);
  prop(bufA, bufB, 32, 2, b4);   // cur (N x 32) in bufB

  // ---- GATv2 ----
  convA(bufB, 32, 64);           // bufB (f32) now dead
  gemm(4, nullptr, bufA, 8, 0);  // xl in bufA
  gemm(5, nullptr, bufB, 8, 0);  // xr in bufB (last reader of Ahi/Alo planes)
  gat_logits_kernel<<<4096, 256, 0, stream>>>(bufA, bufB, att, ei, ea, E, N);
  gat_norm_kernel<<<(N + 3) / 4, 256, 0, stream>>>(rowptr, eids, ea, wvals, selfw, suminv, E, N);
  gat_gather_kernel<<<(N + 7) / 8, 256, 0, stream>>>((const float4*)bufA, rowptr, cols, wvals,
                                                     selfw, suminv, bg, (float4*)bufB, N);
  // x3 (N x 128) in bufB

  // ---- GCN2 #1: relu((1-B)*h + B*(h@Wc1)), h = 0.5*prop(x3)+0.5*x2 ----
  prop(bufB, bufA, 128, 3, x2);                   // h in bufA
  convA(bufA, 128, 128);                          // overwrites ea/wvals (dead)
  gemm(6, nullptr, bufB, 8, 0);                   // h@Wc1 in bufB (x3 dead)
  combine_relu_kernel<<<4096, 256, 0, stream>>>(bufA, bufB, bufA, OMB, BETA, (long long)N * 128);
  // result (N x 128) in bufA

  // ---- W5 layer: relu(prop(x)@W5+b5) ----
  prop(bufA, bufB, 128, 0, nullptr);
  convA(bufB, 128, 128);
  gemm(7, b5, bufA, 16, 2);                       // (N x 256) in bufA (relu fused)

  // ---- GCN2 #2: h = 0.5*prop(.)+0.5*x1 ----
  prop(bufA, bufB, 256, 3, x1);                   // h in bufB
  convA(bufB, 256, 256);
  gemm(8, nullptr, bufA, 16, 0);                  // h@Wc2 in bufA
  combine_relu_kernel<<<4096, 256, 0, stream>>>(bufB, bufA, bufA, OMB, BETA, (long long)N * 256);
  // result (N x 256) in bufA

  // ---- final: prop(x@Wo) + bo ----
  convA(bufA, 256, 256);
  gemm(9, nullptr, bufB, 8, 0);                   // (N x 128) in bufB
  prop(bufB, out, 128, 1, bo);
}

// Round 6
// 1240.136 us; speedup vs baseline: 3.8797x; 1.2119x over previous
//
#include <hip/hip_runtime.h>
#include <math.h>

// ---------------------------------------------------------------------------
// GraphAutoEncoder forward on MI355X. Round 5:
//   - GATv2 fused into ONE per-node online-softmax kernel (one CSR pass,
//     xl row gathered once per edge; replaces logits/norm/gather 3-pass)
//   - bf16 hi/lo conversion fused into prop / combine epilogues
//     (7 of 9 conv_hilo passes eliminated)
//   - MFMA split-bf16 GEMMs, CSR gather props unchanged from round 4
// ---------------------------------------------------------------------------

static constexpr int HEADS = 4;

typedef __attribute__((ext_vector_type(8))) short short8;
typedef __attribute__((ext_vector_type(4))) float f32x4;

__device__ __forceinline__ unsigned short f32_to_bf16(float x) {
  unsigned int u = __float_as_uint(x);
  u = (u + 0x7FFF + ((u >> 16) & 1)) >> 16;   // RNE
  return (unsigned short)u;
}
__device__ __forceinline__ float bf16_to_f32(unsigned short h) {
  return __uint_as_float(((unsigned int)h) << 16);
}

// ---------------- CSR build ----------------

__global__ void deg_kernel(const int* __restrict__ ei, int* __restrict__ deg, int E) {
  int i = blockIdx.x * blockDim.x + threadIdx.x;
  int stride = gridDim.x * blockDim.x;
  for (; i < E; i += stride) atomicAdd(&deg[ei[E + i]], 1);
}

__global__ void dinv_kernel(const int* __restrict__ deg, float* __restrict__ dinv, int N) {
  int i = blockIdx.x * blockDim.x + threadIdx.x;
  if (i < N) dinv[i] = rsqrtf((float)(deg[i] + 1));  // +1 self-loop
}

__global__ __launch_bounds__(256) void scan_block_kernel(const int* __restrict__ in,
                                                         int* __restrict__ out,
                                                         int* __restrict__ bsum, int n) {
  __shared__ int lds[256];
  const int base = blockIdx.x * 2048;
  const int tid = threadIdx.x;
  int v[8];
  int s = 0;
#pragma unroll
  for (int k = 0; k < 8; ++k) {
    int idx = base + tid * 8 + k;
    v[k] = (idx < n) ? in[idx] : 0;
    s += v[k];
  }
  lds[tid] = s;
  __syncthreads();
  for (int off = 1; off < 256; off <<= 1) {
    int t = (tid >= off) ? lds[tid - off] : 0;
    __syncthreads();
    lds[tid] += t;
    __syncthreads();
  }
  int run = (tid > 0) ? lds[tid - 1] : 0;
#pragma unroll
  for (int k = 0; k < 8; ++k) {
    int idx = base + tid * 8 + k;
    run += v[k];
    if (idx < n) out[idx] = run;
  }
  if (tid == 255) bsum[blockIdx.x] = lds[255];
}

__global__ void scan_small_kernel(int* bsum, int nb) {
  if (threadIdx.x == 0 && blockIdx.x == 0) {
    int run = 0;
    for (int i = 0; i < nb; ++i) { int t = bsum[i]; bsum[i] = run; run += t; }
  }
}

__global__ __launch_bounds__(256) void scan_add_kernel(int* __restrict__ out,
                                                       const int* __restrict__ bsum, int n) {
  int idx = blockIdx.x * 2048 + threadIdx.x;
  const int add = bsum[blockIdx.x];
#pragma unroll
  for (int k = 0; k < 8; ++k, idx += 256)
    if (idx < n) out[idx] += add;
}

__global__ void fill_csr_kernel(const int* __restrict__ ei, const float* __restrict__ dinv,
                                const int* __restrict__ rowptr, int* __restrict__ fill,
                                int* __restrict__ cols, float* __restrict__ vals, int E) {
  int e = blockIdx.x * blockDim.x + threadIdx.x;
  int stride = gridDim.x * blockDim.x;
  for (; e < E; e += stride) {
    int s = ei[e], t = ei[E + e];
    int pos = rowptr[t] + atomicAdd(&fill[t], 1);
    cols[pos] = s;
    vals[pos] = dinv[s] * dinv[t];
  }
}

// ---------------- propagation (CSR gather, float4) ----------------
// EPI: 0 none | 1 +bias | 2 relu(+bias) | 3 0.5*acc+0.5*x0
// OUT: 0 f32 only | 1 hi/lo bf16 planes only | 2 both
template <int D, int EPI, int OUT>
__global__ __launch_bounds__(256) void prop_csr_kernel(
    const float4* __restrict__ h, const int* __restrict__ rowptr,
    const int* __restrict__ cols, const float* __restrict__ vals,
    const float* __restrict__ dinv, const float* __restrict__ bx,
    float4* __restrict__ out, ushort4* __restrict__ hi, ushort4* __restrict__ lo,
    int N) {
  constexpr int TPN = D / 4;
  constexpr int NPB = 256 / TPN;
  const int node = blockIdx.x * NPB + threadIdx.x / TPN;
  const int q = threadIdx.x % TPN;
  if (node >= N) return;
  const int start = rowptr[node], end = rowptr[node + 1];
  float4 acc = make_float4(0.f, 0.f, 0.f, 0.f);
  int j = start;
  for (; j + 1 < end; j += 2) {
    float v0 = vals[j], v1 = vals[j + 1];
    float4 a = h[(long long)cols[j] * TPN + q];
    float4 b = h[(long long)cols[j + 1] * TPN + q];
    acc.x += v0 * a.x + v1 * b.x;
    acc.y += v0 * a.y + v1 * b.y;
    acc.z += v0 * a.z + v1 * b.z;
    acc.w += v0 * a.w + v1 * b.w;
  }
  if (j < end) {
    float v = vals[j];
    float4 a = h[(long long)cols[j] * TPN + q];
    acc.x += v * a.x; acc.y += v * a.y; acc.z += v * a.z; acc.w += v * a.w;
  }
  {
    float di = dinv[node];
    float sv = di * di;
    float4 a = h[(long long)node * TPN + q];
    acc.x += sv * a.x; acc.y += sv * a.y; acc.z += sv * a.z; acc.w += sv * a.w;
  }
  float4 r;
  if (EPI == 0) {
    r = acc;
  } else if (EPI == 1 || EPI == 2) {
    float4 b = ((const float4*)bx)[q];
    r.x = acc.x + b.x; r.y = acc.y + b.y; r.z = acc.z + b.z; r.w = acc.w + b.w;
    if (EPI == 2) {
      r.x = fmaxf(r.x, 0.f); r.y = fmaxf(r.y, 0.f);
      r.z = fmaxf(r.z, 0.f); r.w = fmaxf(r.w, 0.f);
    }
  } else {
    float4 x0 = ((const float4*)bx)[(long long)node * TPN + q];
    r.x = 0.5f * (acc.x + x0.x); r.y = 0.5f * (acc.y + x0.y);
    r.z = 0.5f * (acc.z + x0.z); r.w = 0.5f * (acc.w + x0.w);
  }
  if (OUT != 1) out[(long long)node * TPN + q] = r;
  if (OUT >= 1) {
    ushort4 h4, l4;
    h4.x = f32_to_bf16(r.x); l4.x = f32_to_bf16(r.x - bf16_to_f32(h4.x));
    h4.y = f32_to_bf16(r.y); l4.y = f32_to_bf16(r.y - bf16_to_f32(h4.y));
    h4.z = f32_to_bf16(r.z); l4.z = f32_to_bf16(r.z - bf16_to_f32(h4.z));
    h4.w = f32_to_bf16(r.w); l4.w = f32_to_bf16(r.w - bf16_to_f32(h4.w));
    hi[(long long)node * TPN + q] = h4;
    lo[(long long)node * TPN + q] = l4;
  }
}

// ---------------- split-bf16 conversion (standalone, 2 uses) ----------------
__global__ void conv_hilo_kernel(const float* __restrict__ in, unsigned short* __restrict__ hi,
                                 unsigned short* __restrict__ lo, int N, int K, int Kp) {
  const long long total = (long long)N * (Kp / 4);
  long long i = (long long)blockIdx.x * blockDim.x + threadIdx.x;
  const long long stride = (long long)gridDim.x * blockDim.x;
  const int q = Kp / 4;
  for (; i < total; i += stride) {
    int r = (int)(i / q);
    int col = (int)(i % q) * 4;
    ushort4 h4 = make_ushort4(0, 0, 0, 0), l4 = make_ushort4(0, 0, 0, 0);
    if (col < K) {
      float4 v = *(const float4*)(in + (long long)r * K + col);
      h4.x = f32_to_bf16(v.x); l4.x = f32_to_bf16(v.x - bf16_to_f32(h4.x));
      h4.y = f32_to_bf16(v.y); l4.y = f32_to_bf16(v.y - bf16_to_f32(h4.y));
      h4.z = f32_to_bf16(v.z); l4.z = f32_to_bf16(v.z - bf16_to_f32(h4.z));
      h4.w = f32_to_bf16(v.w); l4.w = f32_to_bf16(v.w - bf16_to_f32(h4.w));
    }
    *(ushort4*)(hi + (long long)r * Kp + col) = h4;
    *(ushort4*)(lo + (long long)r * Kp + col) = l4;
  }
}

// ---------------- weight packing (fragment order) ----------------
// lane l holds B[k = 64*chunk + 32*s + 8*(l>>4) + j][col = 16*t + (l&15)]
__global__ void pack_w_kernel(const float* __restrict__ W, unsigned short* __restrict__ hi,
                              unsigned short* __restrict__ lo, int K, int M) {
  int i = blockIdx.x * blockDim.x + threadIdx.x;
  int stride = gridDim.x * blockDim.x;
  const int MT = M >> 4;
  for (; i < K * M; i += stride) {
    int k = i / M, m = i % M;
    float v = W[i];
    unsigned short h = f32_to_bf16(v);
    unsigned short l = f32_to_bf16(v - bf16_to_f32(h));
    int chunk = k >> 6, kin = k & 63;
    int s = (kin >> 5) & 1, kin2 = kin & 31;
    int lane = ((kin2 >> 3) << 4) | (m & 15);
    int j = kin2 & 7, t = m >> 4;
    long long idx = ((((long long)(chunk * MT + t) * 2 + s) * 64 + lane) * 8 + j);
    hi[idx] = h;
    lo[idx] = l;
  }
}

// ---------------- MFMA GEMM (split-bf16, 3 products) ----------------
template <int MT, int EPI>
__global__ __launch_bounds__(256) void gemm_mfma_kernel(
    const unsigned short* __restrict__ Ahi, const unsigned short* __restrict__ Alo,
    const unsigned short* __restrict__ Phi, const unsigned short* __restrict__ Plo,
    const float* __restrict__ bias, float* __restrict__ C, int N, int Kp) {
  constexpr int M = MT * 16;
  constexpr int chunk_elems = M * 64;
  __shared__ unsigned short lds[2 * chunk_elems];
  const int tid = threadIdx.x;
  const int w = tid >> 6, l = tid & 63;
  const int lr = l & 15, lh = l >> 4;
  const int rowbase = blockIdx.x * 128 + w * 32;
  int r0 = rowbase + lr;      if (r0 >= N) r0 = N - 1;
  int r1 = rowbase + 16 + lr; if (r1 >= N) r1 = N - 1;

  f32x4 acc[2][MT] = {};
  unsigned short* ldsHi = lds;
  unsigned short* ldsLo = lds + chunk_elems;
  const int nchunks = Kp >> 6;
  const int n16 = chunk_elems / 8;

  for (int c = 0; c < nchunks; ++c) {
    const uint4* srcH = (const uint4*)(Phi + (long long)c * chunk_elems);
    const uint4* srcL = (const uint4*)(Plo + (long long)c * chunk_elems);
    uint4* dH = (uint4*)ldsHi;
    uint4* dL = (uint4*)ldsLo;
    __syncthreads();
    for (int i = tid; i < n16; i += 256) { dH[i] = srcH[i]; dL[i] = srcL[i]; }
    __syncthreads();
#pragma unroll
    for (int s = 0; s < 2; ++s) {
      const long long abase = (long long)c * 64 + s * 32 + lh * 8;
      short8 a0h = *(const short8*)(Ahi + (long long)r0 * Kp + abase);
      short8 a0l = *(const short8*)(Alo + (long long)r0 * Kp + abase);
      short8 a1h = *(const short8*)(Ahi + (long long)r1 * Kp + abase);
      short8 a1l = *(const short8*)(Alo + (long long)r1 * Kp + abase);
#pragma unroll
      for (int t = 0; t < MT; ++t) {
        const int boff = ((t * 2 + s) * 64 + l) * 8;
        short8 bh = *(const short8*)(ldsHi + boff);
        short8 bl = *(const short8*)(ldsLo + boff);
        acc[0][t] = __builtin_amdgcn_mfma_f32_16x16x32_bf16(a0h, bh, acc[0][t], 0, 0, 0);
        acc[0][t] = __builtin_amdgcn_mfma_f32_16x16x32_bf16(a0h, bl, acc[0][t], 0, 0, 0);
        acc[0][t] = __builtin_amdgcn_mfma_f32_16x16x32_bf16(a0l, bh, acc[0][t], 0, 0, 0);
        acc[1][t] = __builtin_amdgcn_mfma_f32_16x16x32_bf16(a1h, bh, acc[1][t], 0, 0, 0);
        acc[1][t] = __builtin_amdgcn_mfma_f32_16x16x32_bf16(a1h, bl, acc[1][t], 0, 0, 0);
        acc[1][t] = __builtin_amdgcn_mfma_f32_16x16x32_bf16(a1l, bh, acc[1][t], 0, 0, 0);
      }
    }
  }
#pragma unroll
  for (int rt = 0; rt < 2; ++rt) {
#pragma unroll
    for (int t = 0; t < MT; ++t) {
      const int col = t * 16 + lr;
      float b = (EPI >= 1) ? bias[col] : 0.f;
#pragma unroll
      for (int j = 0; j < 4; ++j) {
        int row = rowbase + rt * 16 + lh * 4 + j;
        if (row < N) {
          float v = acc[rt][t][j] + b;
          if (EPI == 2) v = fmaxf(v, 0.f);
          C[(long long)row * M + col] = v;
        }
      }
    }
  }
}

// ---------------- fused GATv2 (online softmax, one CSR pass) ----------------
// wave per node; lane owns cols {2*lane, 2*lane+1}; head = lane>>4.
// out[node] = relu( (sum_j exp(a_j - m) * xl_j) / (sum_j exp(a_j - m) + 1e-16) + bg )
__global__ __launch_bounds__(256) void gat_fused_kernel(
    const float2* __restrict__ xl, const float2* __restrict__ xr,
    const float* __restrict__ att, const int* __restrict__ rowptr,
    const int* __restrict__ cols, const float* __restrict__ bg,
    float2* __restrict__ outv, int N) {
  const int node = blockIdx.x * 4 + (threadIdx.x >> 6);
  if (node >= N) return;
  const int lane = threadIdx.x & 63;
  const float2 xrv = xr[(long long)node * 64 + lane];
  const float2 av = ((const float2*)att)[lane];
  float m = -1e30f, s = 0.f;
  float accx = 0.f, accy = 0.f;
  const int start = rowptr[node], end = rowptr[node + 1];
  for (int j = start; j <= end; ++j) {
    const int col = (j < end) ? cols[j] : node;   // j==end: self-loop
    const float2 xlv = xl[(long long)col * 64 + lane];
    float tx = xlv.x + xrv.x, ty = xlv.y + xrv.y;
    tx = tx >= 0.f ? tx : 0.2f * tx;
    ty = ty >= 0.f ? ty : 0.2f * ty;
    float dot = av.x * tx + av.y * ty;
    dot += __shfl_xor(dot, 1);
    dot += __shfl_xor(dot, 2);
    dot += __shfl_xor(dot, 4);
    dot += __shfl_xor(dot, 8);   // 16-lane head group reduce
    const float mn = fmaxf(m, dot);
    const float scale = __expf(m - mn);
    const float p = __expf(dot - mn);
    s = s * scale + p;
    accx = accx * scale + p * xlv.x;
    accy = accy * scale + p * xlv.y;
    m = mn;
  }
  const float inv = 1.0f / (s + 1e-16f);
  const float2 b = ((const float2*)bg)[lane];
  float2 r;
  r.x = fmaxf(accx * inv + b.x, 0.f);
  r.y = fmaxf(accy * inv + b.y, 0.f);
  outv[(long long)node * 64 + lane] = r;
}

// out = relu(c1*h + c2*t), f32
__global__ void combine_relu_kernel(const float* h, const float* t, float* out,
                                    float c1, float c2, long long n) {
  long long i = (long long)blockIdx.x * blockDim.x + threadIdx.x;
  long long stride = (long long)gridDim.x * blockDim.x;
  for (; i < n; i += stride) out[i] = fmaxf(c1 * h[i] + c2 * t[i], 0.f);
}

// hi/lo = split_bf16(relu(c1*h + c2*t))   (no f32 output)
__global__ void combine_relu_hilo_kernel(const float4* __restrict__ h, const float4* __restrict__ t,
                                         ushort4* __restrict__ hi, ushort4* __restrict__ lo,
                                         float c1, float c2, long long n4) {
  long long i = (long long)blockIdx.x * blockDim.x + threadIdx.x;
  long long stride = (long long)gridDim.x * blockDim.x;
  for (; i < n4; i += stride) {
    float4 a = h[i], b = t[i];
    float4 r;
    r.x = fmaxf(c1 * a.x + c2 * b.x, 0.f);
    r.y = fmaxf(c1 * a.y + c2 * b.y, 0.f);
    r.z = fmaxf(c1 * a.z + c2 * b.z, 0.f);
    r.w = fmaxf(c1 * a.w + c2 * b.w, 0.f);
    ushort4 h4, l4;
    h4.x = f32_to_bf16(r.x); l4.x = f32_to_bf16(r.x - bf16_to_f32(h4.x));
    h4.y = f32_to_bf16(r.y); l4.y = f32_to_bf16(r.y - bf16_to_f32(h4.y));
    h4.z = f32_to_bf16(r.z); l4.z = f32_to_bf16(r.z - bf16_to_f32(h4.z));
    h4.w = f32_to_bf16(r.w); l4.w = f32_to_bf16(r.w - bf16_to_f32(h4.w));
    hi[i] = h4;
    lo[i] = l4;
  }
}

// ---------------------------------------------------------------------------

extern "C" void kernel_launch(void* const* d_in, const int* in_sizes, int n_in,
                              void* d_out, int out_size, void* d_ws, size_t ws_size,
                              hipStream_t stream) {
  const float* x  = (const float*)d_in[0];
  const int*   ei = (const int*)d_in[1];
  const float* W1 = (const float*)d_in[2];  const float* b1 = (const float*)d_in[3];
  const float* W2 = (const float*)d_in[4];  const float* b2 = (const float*)d_in[5];
  const float* W3 = (const float*)d_in[6];  const float* b3 = (const float*)d_in[7];
  const float* W4 = (const float*)d_in[8];  const float* b4 = (const float*)d_in[9];
  const float* Wl = (const float*)d_in[10]; const float* Wr = (const float*)d_in[11];
  const float* att= (const float*)d_in[12]; const float* bg = (const float*)d_in[13];
  const float* Wc1= (const float*)d_in[14];
  const float* W5 = (const float*)d_in[15]; const float* b5 = (const float*)d_in[16];
  const float* Wc2= (const float*)d_in[17];
  const float* Wo = (const float*)d_in[18]; const float* bo = (const float*)d_in[19];

  const int N = in_sizes[0] / 300;
  const int E = in_sizes[1] / 2;
  float* out = (float*)d_out;

  const float BETA = 0.04879016416943205f;
  const float OMB  = 1.0f - BETA;

  // ---- workspace carve-up ----
  float* wsf = (float*)d_ws;
  auto alloc = [&](long long nelem) {
    float* p = wsf; wsf += (nelem + 3) & ~3LL; return p;
  };
  float* dinv   = alloc(N);
  int*   rowptr = (int*)alloc(N + 1);
  int*   cols   = (int*)alloc(E);
  float* vals   = alloc(E);
  float* x1     = alloc((long long)N * 256);
  float* x2     = alloc((long long)N * 128);
  float* bufA   = alloc((long long)N * 256);
  float* bufB   = alloc((long long)N * 256);
  int*   bsum   = (int*)alloc(64);
  unsigned short* Ahi = (unsigned short*)alloc((long long)N * 160);  // N*320 ushorts
  unsigned short* Alo = (unsigned short*)alloc((long long)N * 160);
  struct WDesc { const float* W; int K, M; };
  WDesc wd[10] = {{W1,300,256},{W2,256,128},{W3,128,64},{W4,64,32},{Wl,32,128},
                  {Wr,32,128},{Wc1,128,128},{W5,128,256},{Wc2,256,256},{Wo,256,128}};
  long long woff[10], wtot = 0;
  int wkp[10];
  for (int i = 0; i < 10; ++i) {
    wkp[i] = (wd[i].K + 63) & ~63;
    woff[i] = wtot;
    wtot += 2LL * wkp[i] * wd[i].M;
  }
  unsigned short* warena = (unsigned short*)alloc(wtot / 2 + 4);
  // setup-only overlays on Ahi/Alo (dead until first conv/prop-hilo):
  int* deg  = (int*)Ahi;
  int* fill = (int*)Alo;

  auto convA = [&](const float* src, int K, int Kp) {
    long long total = (long long)N * (Kp / 4);
    int blocks = (int)(((total + 255) / 256 < 4096) ? (total + 255) / 256 : 4096);
    conv_hilo_kernel<<<blocks, 256, 0, stream>>>(src, Ahi, Alo, N, K, Kp);
  };
  const int gemm_grid = (N + 127) / 128;
  auto gemm = [&](int wi, const float* bias, float* C, int MT, int epi) {
    const unsigned short* Phi = warena + woff[wi];
    const unsigned short* Plo = Phi + (long long)wkp[wi] * wd[wi].M;
    if (MT == 16 && epi == 0)
      gemm_mfma_kernel<16,0><<<gemm_grid, 256, 0, stream>>>(Ahi, Alo, Phi, Plo, bias, C, N, wkp[wi]);
    else if (MT == 16 && epi == 2)
      gemm_mfma_kernel<16,2><<<gemm_grid, 256, 0, stream>>>(Ahi, Alo, Phi, Plo, bias, C, N, wkp[wi]);
    else if (MT == 8)
      gemm_mfma_kernel<8,0><<<gemm_grid, 256, 0, stream>>>(Ahi, Alo, Phi, Plo, bias, C, N, wkp[wi]);
    else if (MT == 4)
      gemm_mfma_kernel<4,0><<<gemm_grid, 256, 0, stream>>>(Ahi, Alo, Phi, Plo, bias, C, N, wkp[wi]);
    else
      gemm_mfma_kernel<2,0><<<gemm_grid, 256, 0, stream>>>(Ahi, Alo, Phi, Plo, bias, C, N, wkp[wi]);
  };
  ushort4* hi4 = (ushort4*)Ahi;
  ushort4* lo4 = (ushort4*)Alo;

  // ---- weight packing (once per launch) ----
  hipMemsetAsync(warena, 0, (size_t)wtot * sizeof(unsigned short), stream);
  for (int i = 0; i < 10; ++i) {
    unsigned short* Phi = warena + woff[i];
    unsigned short* Plo = Phi + (long long)wkp[i] * wd[i].M;
    int total = wd[i].K * wd[i].M;
    pack_w_kernel<<<(total + 255) / 256, 256, 0, stream>>>(wd[i].W, Phi, Plo, wd[i].K, wd[i].M);
  }

  // ---- CSR build ----
  hipMemsetAsync(deg, 0, (size_t)N * sizeof(int), stream);
  hipMemsetAsync(fill, 0, (size_t)N * sizeof(int), stream);
  hipMemsetAsync(rowptr, 0, sizeof(int), stream);
  deg_kernel<<<2048, 256, 0, stream>>>(ei, deg, E);
  dinv_kernel<<<(N + 255) / 256, 256, 0, stream>>>(deg, dinv, N);
  {
    int nb = (N + 2047) / 2048;
    scan_block_kernel<<<nb, 256, 0, stream>>>(deg, rowptr + 1, bsum, N);
    scan_small_kernel<<<1, 64, 0, stream>>>(bsum, nb);
    scan_add_kernel<<<nb, 256, 0, stream>>>(rowptr + 1, bsum, N);
  }
  fill_csr_kernel<<<2048, 256, 0, stream>>>(ei, dinv, rowptr, fill, cols, vals, E);

  // ---- layer 1: x1 = relu(prop(x@W1)+b1)  [+ hilo planes] ----
  convA(x, 300, 320);
  gemm(0, nullptr, bufA, 16, 0);
  prop_csr_kernel<256,2,2><<<(N + 3) / 4, 256, 0, stream>>>(
      (const float4*)bufA, rowptr, cols, vals, dinv, b1, (float4*)x1, hi4, lo4, N);

  // ---- layer 2: x2 [+ planes] ----
  gemm(1, nullptr, bufA, 8, 0);
  prop_csr_kernel<128,2,2><<<(N + 7) / 8, 256, 0, stream>>>(
      (const float4*)bufA, rowptr, cols, vals, dinv, b2, (float4*)x2, hi4, lo4, N);

  // ---- layer 3: planes only ----
  gemm(2, nullptr, bufA, 4, 0);
  prop_csr_kernel<64,2,1><<<(N + 15) / 16, 256, 0, stream>>>(
      (const float4*)bufA, rowptr, cols, vals, dinv, b3, nullptr, hi4, lo4, N);

  // ---- layer 4: f32 (D=32 needs pad-conv) ----
  gemm(3, nullptr, bufA, 2, 0);
  prop_csr_kernel<32,2,0><<<(N + 31) / 32, 256, 0, stream>>>(
      (const float4*)bufA, rowptr, cols, vals, dinv, b4, (float4*)bufB, nullptr, nullptr, N);
  convA(bufB, 32, 64);

  // ---- GATv2 (fused single pass) ----
  gemm(4, nullptr, bufA, 8, 0);  // xl in bufA
  gemm(5, nullptr, bufB, 8, 0);  // xr in bufB
  gat_fused_kernel<<<(N + 3) / 4, 256, 0, stream>>>(
      (const float2*)bufA, (const float2*)bufB, att, rowptr, cols, bg, (float2*)bufB, N);
  // x3 (N x 128) in bufB

  // ---- GCN2 #1: relu((1-B)*h + B*(h@Wc1)), h = 0.5*prop(x3)+0.5*x2 ----
  prop_csr_kernel<128,3,2><<<(N + 7) / 8, 256, 0, stream>>>(
      (const float4*)bufB, rowptr, cols, vals, dinv, x2, (float4*)bufA, hi4, lo4, N);
  gemm(6, nullptr, bufB, 8, 0);                   // h@Wc1
  combine_relu_kernel<<<4096, 256, 0, stream>>>(bufA, bufB, bufA, OMB, BETA, (long long)N * 128);

  // ---- W5 layer: relu(prop(x)@W5+b5) ----
  prop_csr_kernel<128,0,1><<<(N + 7) / 8, 256, 0, stream>>>(
      (const float4*)bufA, rowptr, cols, vals, dinv, nullptr, nullptr, hi4, lo4, N);
  gemm(7, b5, bufB, 16, 2);                       // (N x 256), relu fused

  // ---- GCN2 #2: h = 0.5*prop(.)+0.5*x1 ----
  prop_csr_kernel<256,3,2><<<(N + 3) / 4, 256, 0, stream>>>(
      (const float4*)bufB, rowptr, cols, vals, dinv, x1, (float4*)bufA, hi4, lo4, N);
  gemm(8, nullptr, bufB, 16, 0);                  // h@Wc2
  combine_relu_hilo_kernel<<<4096, 256, 0, stream>>>(
      (const float4*)bufA, (const float4*)bufB, hi4, lo4, OMB, BETA, (long long)N * 64);

  // ---- final: prop(x@Wo) + bo ----
  gemm(9, nullptr, bufB, 8, 0);                   // (N x 128)
  prop_csr_kernel<128,1,0><<<(N + 7) / 8, 256, 0, stream>>>(
      (const float4*)bufB, rowptr, cols, vals, dinv, bo, (float4*)out, nullptr, nullptr, N);
}